// Round 2
// baseline (743.046 us; speedup 1.0000x reference)
//
#include <hip/hip_runtime.h>
#include <hip/hip_bf16.h>
#include <stdint.h>

// Problem constants (fixed by the reference setup)
#define NROWS 8192   // N (batch rows of x)
#define IN_F  4096   // K
#define OUT_F 4096   // N (output features)
#define RANK  16
#define SCALE 0.0025f  // SIGMA / sqrt(r) * SIGN = 0.01 / 4 * 1.0

typedef __bf16 bf16x8 __attribute__((ext_vector_type(8)));
typedef float f32x4 __attribute__((ext_vector_type(4)));

// ---------------------------------------------------------------------------
// Kernel 1: Pbt[r][i] = sum_j P[i][j] * noise[j][r]   (Pb = P @ b_mat, stored
// transposed 16 x 4096 so kernel 2 can read rows coalesced)
// ---------------------------------------------------------------------------
__global__ __launch_bounds__(256) void pb_kernel(const float* __restrict__ P,
                                                 const float* __restrict__ noise,
                                                 float* __restrict__ Pbt) {
  int i = blockIdx.x;
  int tid = threadIdx.x;
  int lane = tid & 63;
  int wave = tid >> 6;
  float acc[RANK];
#pragma unroll
  for (int r = 0; r < RANK; r++) acc[r] = 0.f;
  const float* Prow = P + (size_t)i * IN_F;
  for (int j = tid; j < IN_F; j += 256) {
    float p = Prow[j];
    const f32x4* brow = (const f32x4*)(noise + (size_t)j * RANK);
    f32x4 b0 = brow[0], b1 = brow[1], b2 = brow[2], b3 = brow[3];
#pragma unroll
    for (int q = 0; q < 4; q++) {
      acc[q] += p * b0[q];
      acc[4 + q] += p * b1[q];
      acc[8 + q] += p * b2[q];
      acc[12 + q] += p * b3[q];
    }
  }
  // wave reduce (64 lanes)
#pragma unroll
  for (int off = 32; off > 0; off >>= 1)
#pragma unroll
    for (int r = 0; r < RANK; r++) acc[r] += __shfl_down(acc[r], off, 64);
  __shared__ float red[4][RANK];
  if (lane == 0)
#pragma unroll
    for (int r = 0; r < RANK; r++) red[wave][r] = acc[r];
  __syncthreads();
  if (tid < RANK) {
    float s = red[0][tid] + red[1][tid] + red[2][tid] + red[3][tid];
    Pbt[(size_t)tid * IN_F + i] = s;
  }
}

// ---------------------------------------------------------------------------
// Kernel 2: Wb[n][k] = bf16( W[n][k] + SCALE * sum_r a_mat[n][r] * Pbt[r][k] )
// a_mat[n][r] = noise[(IN_F + n)*RANK + r]
// ---------------------------------------------------------------------------
__global__ __launch_bounds__(256) void wprep_kernel(const float* __restrict__ W,
                                                    const float* __restrict__ noise,
                                                    const float* __restrict__ Pbt,
                                                    __bf16* __restrict__ Wb) {
  int n = blockIdx.x;
  int tid = threadIdx.x;
  __shared__ float arow[RANK];
  if (tid < RANK) arow[tid] = SCALE * noise[(size_t)(IN_F + n) * RANK + tid];
  __syncthreads();
  int k0 = tid * 16;
  const f32x4* wr = (const f32x4*)(W + (size_t)n * IN_F + k0);
  f32x4 o0 = wr[0], o1 = wr[1], o2 = wr[2], o3 = wr[3];
#pragma unroll
  for (int r = 0; r < RANK; r++) {
    float ar = arow[r];
    const f32x4* pr = (const f32x4*)(Pbt + (size_t)r * IN_F + k0);
    f32x4 p0 = pr[0], p1 = pr[1], p2 = pr[2], p3 = pr[3];
#pragma unroll
    for (int q = 0; q < 4; q++) {
      o0[q] += ar * p0[q];
      o1[q] += ar * p1[q];
      o2[q] += ar * p2[q];
      o3[q] += ar * p3[q];
    }
  }
  __align__(16) __bf16 ob[16];
#pragma unroll
  for (int q = 0; q < 4; q++) {
    ob[q] = (__bf16)o0[q];
    ob[4 + q] = (__bf16)o1[q];
    ob[8 + q] = (__bf16)o2[q];
    ob[12 + q] = (__bf16)o3[q];
  }
  *(uint4*)(Wb + (size_t)n * IN_F + k0) = *(uint4*)&ob[0];
  *(uint4*)(Wb + (size_t)n * IN_F + k0 + 8) = *(uint4*)&ob[8];
}

// ---------------------------------------------------------------------------
// Kernel 3: cast x (f32) -> bf16
// ---------------------------------------------------------------------------
__global__ __launch_bounds__(256) void xcast_kernel(const float* __restrict__ X,
                                                    __bf16* __restrict__ Xb) {
  size_t idx = ((size_t)blockIdx.x * 256 + threadIdx.x) * 8;
  f32x4 a = *(const f32x4*)(X + idx);
  f32x4 b = *(const f32x4*)(X + idx + 4);
  __align__(16) __bf16 ob[8];
#pragma unroll
  for (int q = 0; q < 4; q++) {
    ob[q] = (__bf16)a[q];
    ob[4 + q] = (__bf16)b[q];
  }
  *(uint4*)(Xb + idx) = *(uint4*)&ob[0];
}

// ---------------------------------------------------------------------------
// Kernel 4: main GEMM  C[m][n] = sum_k A[m][k]*B[n][k] + bias[n]
// A: NROWS x K (bf16, row-major), B: OUT_F x K (bf16, row-major) -> A @ B^T
// 128x128 block tile, BK=32, 256 threads = 4 waves, 64x64 per wave,
// 4x4 frags of v_mfma_f32_16x16x32_bf16, global_load_lds width-16 staging.
//
// LDS layout is XOR-swizzled to kill ds_read_b128 bank conflicts:
//   LDS(row, 16B-block b) holds global 16B-block (b ^ ((row>>1)&3)).
// Staging picks the swizzled GLOBAL block per lane (LDS dest must stay
// lane-contiguous per global_load_lds semantics); fragment reads XOR the
// same term back. Rows in any 8-lane phase then cover all 8 distinct
// 4-bank groups -> conflict-free (R1 measured 3.35e7 conflict cycles
// from the unswizzled layout's 4-way aliasing).
// ---------------------------------------------------------------------------
__global__ __launch_bounds__(256, 3) void gemm_kernel(const __bf16* __restrict__ A,
                                                      const __bf16* __restrict__ B,
                                                      const float* __restrict__ bias,
                                                      float* __restrict__ C) {
  constexpr int K = IN_F;
  constexpr int N = OUT_F;
  __shared__ __align__(16) __bf16 sA[128 * 32];
  __shared__ __align__(16) __bf16 sB[128 * 32];

  int tid = threadIdx.x;
  int wave = tid >> 6;
  int lane = tid & 63;
  int m0 = blockIdx.y * 128;
  int n0 = blockIdx.x * 128;
  int wm = (wave >> 1) * 64;  // wave's row offset in tile
  int wn = (wave & 1) * 64;   // wave's col offset in tile
  int lr = lane & 15;         // fragment row/col lane index
  // swizzled k-block for fragment reads: q' = q ^ ((lr>>1)&3), in elements
  int kq = (((lane >> 4) ^ ((lr >> 1) & 3)) & 3) * 8;

  f32x4 acc[4][4];
#pragma unroll
  for (int i = 0; i < 4; i++)
#pragma unroll
    for (int j = 0; j < 4; j++) acc[i][j] = (f32x4){0.f, 0.f, 0.f, 0.f};

  const __bf16* Ab = A + (size_t)m0 * K;
  const __bf16* Bb = B + (size_t)n0 * K;
  int rsub = lane >> 2;  // 0..15: row within 16-row chunk
  // swizzled global 16B-block for staging: g = b ^ ((row>>1)&3); row ≡ rsub mod 16
  int cb = (((lane & 3) ^ ((rsub >> 1) & 3)) & 3) * 8;  // element col offset

  for (int k0 = 0; k0 < K; k0 += 32) {
    __syncthreads();  // previous compute done reading LDS
#pragma unroll
    for (int s = 0; s < 2; s++) {
      int rr = (s * 4 + wave) * 16;  // wave-uniform row base
      const __bf16* gA = Ab + (size_t)(rr + rsub) * K + k0 + cb;
      const __bf16* gB = Bb + (size_t)(rr + rsub) * K + k0 + cb;
      __builtin_amdgcn_global_load_lds((__attribute__((address_space(1))) void*)gA,
                                       (__attribute__((address_space(3))) void*)(sA + rr * 32),
                                       16, 0, 0);
      __builtin_amdgcn_global_load_lds((__attribute__((address_space(1))) void*)gB,
                                       (__attribute__((address_space(3))) void*)(sB + rr * 32),
                                       16, 0, 0);
    }
    __syncthreads();  // drains vmcnt(0) before barrier -> LDS visible

    bf16x8 af[4], bfr[4];
#pragma unroll
    for (int i = 0; i < 4; i++) {
      af[i] = *(const bf16x8*)(sA + (wm + i * 16 + lr) * 32 + kq);
      bfr[i] = *(const bf16x8*)(sB + (wn + i * 16 + lr) * 32 + kq);
    }
#pragma unroll
    for (int i = 0; i < 4; i++)
#pragma unroll
      for (int j = 0; j < 4; j++)
        acc[i][j] = __builtin_amdgcn_mfma_f32_16x16x32_bf16(af[i], bfr[j], acc[i][j], 0, 0, 0);
  }

  // Epilogue: C/D layout col = lane&15, row = (lane>>4)*4 + reg  [m89/m91]
  int cn = lane & 15;
  int rq = (lane >> 4) * 4;
#pragma unroll
  for (int j = 0; j < 4; j++) {
    int col = n0 + wn + j * 16 + cn;
    float bv = bias[col];
#pragma unroll
    for (int i = 0; i < 4; i++) {
      int rowb = m0 + wm + i * 16 + rq;
#pragma unroll
      for (int v = 0; v < 4; v++) {
        C[(size_t)(rowb + v) * N + col] = acc[i][j][v] + bv;
      }
    }
  }
}

// ---------------------------------------------------------------------------
extern "C" void kernel_launch(void* const* d_in, const int* in_sizes, int n_in,
                              void* d_out, int out_size, void* d_ws, size_t ws_size,
                              hipStream_t stream) {
  const float* x = (const float*)d_in[0];       // 8192 x 4096
  const float* weight = (const float*)d_in[1];  // 4096 x 4096
  const float* bias = (const float*)d_in[2];    // 4096
  const float* noise = (const float*)d_in[3];   // 8192 x 16
  const float* P = (const float*)d_in[4];       // 4096 x 4096
  float* out = (float*)d_out;                   // 8192 x 4096

  char* ws = (char*)d_ws;
  __bf16* Xb = (__bf16*)ws;                                   // 64 MB
  __bf16* Wb = (__bf16*)(ws + (size_t)NROWS * IN_F * 2);      // 32 MB
  float* Pbt = (float*)(ws + (size_t)NROWS * IN_F * 2 + (size_t)OUT_F * IN_F * 2);  // 256 KB

  pb_kernel<<<IN_F, 256, 0, stream>>>(P, noise, Pbt);
  wprep_kernel<<<OUT_F, 256, 0, stream>>>(weight, noise, Pbt, Wb);
  xcast_kernel<<<(int)(((size_t)NROWS * IN_F) / (8 * 256)), 256, 0, stream>>>(x, Xb);
  dim3 grid(OUT_F / 128, NROWS / 128);
  gemm_kernel<<<grid, 256, 0, stream>>>(Xb, Wb, bias, out);
}

// Round 3
// 725.043 us; speedup vs baseline: 1.0248x; 1.0248x over previous
//
#include <hip/hip_runtime.h>
#include <hip/hip_bf16.h>
#include <stdint.h>

// Problem constants (fixed by the reference setup)
#define NROWS 8192   // N (batch rows of x)
#define IN_F  4096   // K
#define OUT_F 4096   // N (output features)
#define RANK  16
#define SCALE 0.0025f  // SIGMA / sqrt(r) * SIGN = 0.01 / 4 * 1.0

typedef __bf16 bf16x8 __attribute__((ext_vector_type(8)));
typedef float f32x4 __attribute__((ext_vector_type(4)));
typedef float f32x16 __attribute__((ext_vector_type(16)));

// ---------------------------------------------------------------------------
// Kernel 1: Pbt[r][i] = sum_j P[i][j] * noise[j][r]   (Pb = P @ b_mat, stored
// transposed 16 x 4096 so kernel 2 can read rows coalesced)
// ---------------------------------------------------------------------------
__global__ __launch_bounds__(256) void pb_kernel(const float* __restrict__ P,
                                                 const float* __restrict__ noise,
                                                 float* __restrict__ Pbt) {
  int i = blockIdx.x;
  int tid = threadIdx.x;
  int lane = tid & 63;
  int wave = tid >> 6;
  float acc[RANK];
#pragma unroll
  for (int r = 0; r < RANK; r++) acc[r] = 0.f;
  const float* Prow = P + (size_t)i * IN_F;
  for (int j = tid; j < IN_F; j += 256) {
    float p = Prow[j];
    const f32x4* brow = (const f32x4*)(noise + (size_t)j * RANK);
    f32x4 b0 = brow[0], b1 = brow[1], b2 = brow[2], b3 = brow[3];
#pragma unroll
    for (int q = 0; q < 4; q++) {
      acc[q] += p * b0[q];
      acc[4 + q] += p * b1[q];
      acc[8 + q] += p * b2[q];
      acc[12 + q] += p * b3[q];
    }
  }
  // wave reduce (64 lanes)
#pragma unroll
  for (int off = 32; off > 0; off >>= 1)
#pragma unroll
    for (int r = 0; r < RANK; r++) acc[r] += __shfl_down(acc[r], off, 64);
  __shared__ float red[4][RANK];
  if (lane == 0)
#pragma unroll
    for (int r = 0; r < RANK; r++) red[wave][r] = acc[r];
  __syncthreads();
  if (tid < RANK) {
    float s = red[0][tid] + red[1][tid] + red[2][tid] + red[3][tid];
    Pbt[(size_t)tid * IN_F + i] = s;
  }
}

// ---------------------------------------------------------------------------
// Kernel 2: Wb[n][k] = bf16( W[n][k] + SCALE * sum_r a_mat[n][r] * Pbt[r][k] )
// a_mat[n][r] = noise[(IN_F + n)*RANK + r]
// ---------------------------------------------------------------------------
__global__ __launch_bounds__(256) void wprep_kernel(const float* __restrict__ W,
                                                    const float* __restrict__ noise,
                                                    const float* __restrict__ Pbt,
                                                    __bf16* __restrict__ Wb) {
  int n = blockIdx.x;
  int tid = threadIdx.x;
  __shared__ float arow[RANK];
  if (tid < RANK) arow[tid] = SCALE * noise[(size_t)(IN_F + n) * RANK + tid];
  __syncthreads();
  int k0 = tid * 16;
  const f32x4* wr = (const f32x4*)(W + (size_t)n * IN_F + k0);
  f32x4 o0 = wr[0], o1 = wr[1], o2 = wr[2], o3 = wr[3];
#pragma unroll
  for (int r = 0; r < RANK; r++) {
    float ar = arow[r];
    const f32x4* pr = (const f32x4*)(Pbt + (size_t)r * IN_F + k0);
    f32x4 p0 = pr[0], p1 = pr[1], p2 = pr[2], p3 = pr[3];
#pragma unroll
    for (int q = 0; q < 4; q++) {
      o0[q] += ar * p0[q];
      o1[q] += ar * p1[q];
      o2[q] += ar * p2[q];
      o3[q] += ar * p3[q];
    }
  }
  __align__(16) __bf16 ob[16];
#pragma unroll
  for (int q = 0; q < 4; q++) {
    ob[q] = (__bf16)o0[q];
    ob[4 + q] = (__bf16)o1[q];
    ob[8 + q] = (__bf16)o2[q];
    ob[12 + q] = (__bf16)o3[q];
  }
  *(uint4*)(Wb + (size_t)n * IN_F + k0) = *(uint4*)&ob[0];
  *(uint4*)(Wb + (size_t)n * IN_F + k0 + 8) = *(uint4*)&ob[8];
}

// ---------------------------------------------------------------------------
// Kernel 3: cast x (f32) -> bf16
// ---------------------------------------------------------------------------
__global__ __launch_bounds__(256) void xcast_kernel(const float* __restrict__ X,
                                                    __bf16* __restrict__ Xb) {
  size_t idx = ((size_t)blockIdx.x * 256 + threadIdx.x) * 8;
  f32x4 a = *(const f32x4*)(X + idx);
  f32x4 b = *(const f32x4*)(X + idx + 4);
  __align__(16) __bf16 ob[8];
#pragma unroll
  for (int q = 0; q < 4; q++) {
    ob[q] = (__bf16)a[q];
    ob[4 + q] = (__bf16)b[q];
  }
  *(uint4*)(Xb + idx) = *(uint4*)&ob[0];
}

// ---------------------------------------------------------------------------
// Kernel 4: main GEMM  C[m][n] = sum_k A[m][k]*B[n][k] + bias[n]
// A: NROWS x K (bf16), B: OUT_F x K (bf16), both row-major -> A @ B^T.
// 128x128 block tile, BK=64, 256 threads = 4 waves, 64x64 per wave as
// 2x2 frags of v_mfma_f32_32x32x16_bf16 (2382 TF ubench ceiling vs 2075
// for 16x16 — m06), global_load_lds width-16 staging.
//
// BK=64 halves barrier count vs BK=32 (64 iters), amortizing the
// structural vmcnt(0)+s_barrier drain over 2x the MFMA work. LDS = 32 KB
// total (occupancy stays register-bound ~4 blocks/CU; m132's regression
// was the 64 KB cliff).
//
// Row stride is 128 B = exactly 32 banks, so LDS is XOR-swizzled:
//   LDS(row, 16B-block b) holds global block (b ^ (row&7)).
// Staging lanes fetch the permuted block (still within the row's 128 B
// segment -> coalescing intact; LDS dest stays lane-contiguous per
// global_load_lds wave-uniform-base semantics); fragment reads XOR it
// back -> each 8-lane phase covers all 8 bank groups, conflict-free
// (R2 verified this swizzle scheme: SQ_LDS_BANK_CONFLICT == 0).
// ---------------------------------------------------------------------------
__global__ __launch_bounds__(256, 3) void gemm_kernel(const __bf16* __restrict__ A,
                                                      const __bf16* __restrict__ B,
                                                      const float* __restrict__ bias,
                                                      float* __restrict__ C) {
  constexpr int K = IN_F;
  constexpr int N = OUT_F;
  constexpr int BK = 64;
  __shared__ __align__(16) __bf16 sA[128 * BK];
  __shared__ __align__(16) __bf16 sB[128 * BK];

  int tid = threadIdx.x;
  int wave = tid >> 6;
  int lane = tid & 63;
  int m0 = blockIdx.y * 128;
  int n0 = blockIdx.x * 128;
  int wm = (wave >> 1) * 64;  // wave's row offset in tile
  int wn = (wave & 1) * 64;   // wave's col offset in tile
  int rl = lane & 31;         // fragment row/col within 32-subtile
  int kh = lane >> 5;         // k-half: 0 -> k 0..7, 1 -> k 8..15
  int swz = rl & 7;           // read-side XOR term

  f32x16 acc[2][2];
#pragma unroll
  for (int i = 0; i < 2; i++)
#pragma unroll
    for (int j = 0; j < 2; j++) acc[i][j] = (f32x16)(0.f);

  const __bf16* Ab = A + (size_t)m0 * K;
  const __bf16* Bb = B + (size_t)n0 * K;
  // Staging: one wave-issue = 64 lanes x 16 B = 8 rows of 128 B.
  int srow = lane >> 3;                       // 0..7 row within 8-row chunk
  int sblk = (lane & 7) ^ (srow & 7);         // swizzled GLOBAL 16B-block
  int scol = sblk * 8;                        // element col offset

  for (int k0 = 0; k0 < K; k0 += BK) {
    __syncthreads();  // previous compute done reading LDS
#pragma unroll
    for (int s = 0; s < 4; s++) {
      int rr = wave * 32 + s * 8;  // wave-uniform row base
      const __bf16* gA = Ab + (size_t)(rr + srow) * K + k0 + scol;
      const __bf16* gB = Bb + (size_t)(rr + srow) * K + k0 + scol;
      __builtin_amdgcn_global_load_lds((__attribute__((address_space(1))) void*)gA,
                                       (__attribute__((address_space(3))) void*)(sA + rr * BK),
                                       16, 0, 0);
      __builtin_amdgcn_global_load_lds((__attribute__((address_space(1))) void*)gB,
                                       (__attribute__((address_space(3))) void*)(sB + rr * BK),
                                       16, 0, 0);
    }
    __syncthreads();  // drains vmcnt(0) before barrier -> LDS visible

#pragma unroll
    for (int t = 0; t < 4; t++) {  // 4 k-steps of 16
      int kb = t * 2 + kh;         // logical 16B-block along k
      bf16x8 af[2], bfr[2];
#pragma unroll
      for (int i = 0; i < 2; i++) {
        int arow = wm + i * 32 + rl;
        af[i] = *(const bf16x8*)(sA + arow * BK + (kb ^ swz) * 8);
        int brow = wn + i * 32 + rl;
        bfr[i] = *(const bf16x8*)(sB + brow * BK + (kb ^ swz) * 8);
      }
#pragma unroll
      for (int i = 0; i < 2; i++)
#pragma unroll
        for (int j = 0; j < 2; j++)
          acc[i][j] = __builtin_amdgcn_mfma_f32_32x32x16_bf16(af[i], bfr[j], acc[i][j], 0, 0, 0);
    }
  }

  // Epilogue: 32x32 C/D layout col = lane&31,
  // row = (reg&3) + 8*(reg>>2) + 4*(lane>>5)   [m74/m101]
  int cn = lane & 31;
  int rbase = 4 * kh;
#pragma unroll
  for (int j = 0; j < 2; j++) {
    int col = n0 + wn + j * 32 + cn;
    float bv = bias[col];
#pragma unroll
    for (int i = 0; i < 2; i++) {
      int rowb = m0 + wm + i * 32 + rbase;
#pragma unroll
      for (int reg = 0; reg < 16; reg++) {
        int row = rowb + (reg & 3) + 8 * (reg >> 2);
        C[(size_t)row * N + col] = acc[i][j][reg] + bv;
      }
    }
  }
}

// ---------------------------------------------------------------------------
extern "C" void kernel_launch(void* const* d_in, const int* in_sizes, int n_in,
                              void* d_out, int out_size, void* d_ws, size_t ws_size,
                              hipStream_t stream) {
  const float* x = (const float*)d_in[0];       // 8192 x 4096
  const float* weight = (const float*)d_in[1];  // 4096 x 4096
  const float* bias = (const float*)d_in[2];    // 4096
  const float* noise = (const float*)d_in[3];   // 8192 x 16
  const float* P = (const float*)d_in[4];       // 4096 x 4096
  float* out = (float*)d_out;                   // 8192 x 4096

  char* ws = (char*)d_ws;
  __bf16* Xb = (__bf16*)ws;                                   // 64 MB
  __bf16* Wb = (__bf16*)(ws + (size_t)NROWS * IN_F * 2);      // 32 MB
  float* Pbt = (float*)(ws + (size_t)NROWS * IN_F * 2 + (size_t)OUT_F * IN_F * 2);  // 256 KB

  pb_kernel<<<IN_F, 256, 0, stream>>>(P, noise, Pbt);
  wprep_kernel<<<OUT_F, 256, 0, stream>>>(weight, noise, Pbt, Wb);
  xcast_kernel<<<(int)(((size_t)NROWS * IN_F) / (8 * 256)), 256, 0, stream>>>(x, Xb);
  dim3 grid(OUT_F / 128, NROWS / 128);
  gemm_kernel<<<grid, 256, 0, stream>>>(Xb, Wb, bias, out);
}